// Round 8
// baseline (182.675 us; speedup 1.0000x reference)
//
#include <hip/hip_runtime.h>

#define LOG2E 1.4426950408889634f
#define LN2F 0.6931471805599453f

constexpr int NB = 16;    // batches
constexpr int NN = 512;   // N rows
constexpr int MM = 512;   // M cols
constexpr int KD = 64;    // feature dim
constexpr int WAVES = 8;                     // 512 threads, 1 row/lane
constexpr int CSPAN = 32;                    // diagonals per barrier phase
constexpr int NSPANS = 32;
constexpr int SPW = 18;                      // spans per 64-row block
constexpr int TPH = 3 * (WAVES - 1) + SPW;   // 39 barrier phases
constexpr int DIAGELEMS = NN * MM;
constexpr int EMIN = -(1 << 27);             // exponent of u==0 ("R=inf")

constexpr int BBPAD = 62;
constexpr int BBSTRIDE = 648;  // float2 pairs per boundary row (cols -62..576)

// Packed anti-diagonal layout: element (i,j) [0-based] lives at
// Dsk[b*DIAGELEMS + B(s) + i],  s = i+j.
__device__ __forceinline__ int Bclosed(int s) {
  return (s <= 511) ? (s * (s + 1)) / 2
                    : DIAGELEMS - ((1023 - s) * (1024 - s)) / 2 - (s - 511);
}

// ---------------- Kernel 1: pairwise distances -> t = 2^(-D') packed -------
// D' = min(dist^2,1e4)*log2e.  Store u32 = (et<<16) | f16(mt), where
// t = mt * 2^(-et), et = floor(D') in [0,14428), mt = 2^(et-D') in (0.5,1].
__global__ __launch_bounds__(256) void pairdist_kernel(
    const float* __restrict__ X, const float* __restrict__ Y,
    unsigned* __restrict__ Dsk) {
  const int b = blockIdx.z;
  const int i0 = blockIdx.y * 64;
  const int j0 = blockIdx.x * 64;

  __shared__ float Xs[64][65];
  __shared__ float Ys[64][65];
  __shared__ float Ds[64][66];

  const float* Xb = X + ((size_t)b * NN + i0) * KD;
  const float* Yb = Y + ((size_t)b * MM + j0) * KD;
  for (int k = threadIdx.x; k < 64 * KD; k += 256) {
    Xs[k >> 6][k & 63] = Xb[k];
    Ys[k >> 6][k & 63] = Yb[k];
  }
  __syncthreads();

  const int tx = threadIdx.x & 15;
  const int ty = threadIdx.x >> 4;
  const int r0 = ty * 4, c0 = tx * 4;

  float acc[4][4];
#pragma unroll
  for (int a = 0; a < 4; ++a)
#pragma unroll
    for (int e = 0; e < 4; ++e) acc[a][e] = 0.0f;

  for (int d = 0; d < KD; ++d) {
    float xv[4], yv[4];
#pragma unroll
    for (int q = 0; q < 4; ++q) xv[q] = Xs[r0 + q][d];
#pragma unroll
    for (int q = 0; q < 4; ++q) yv[q] = Ys[c0 + q][d];
#pragma unroll
    for (int a = 0; a < 4; ++a)
#pragma unroll
      for (int e = 0; e < 4; ++e) {
        float df = xv[a] - yv[e];
        acc[a][e] = fmaf(df, df, acc[a][e]);
      }
  }

#pragma unroll
  for (int a = 0; a < 4; ++a)
#pragma unroll
    for (int e = 0; e < 4; ++e)
      Ds[r0 + a][c0 + e] = fminf(acc[a][e], 10000.0f) * LOG2E;
  __syncthreads();

  // diag-major coalesced stores, packing (mt, et) per cell
  const int wv = threadIdx.x >> 6;
  const int ln = threadIdx.x & 63;
  unsigned* Db = Dsk + (size_t)b * DIAGELEMS;
  for (int sl = wv; sl < 127; sl += 4) {
    const int istart = sl > 63 ? sl - 63 : 0;
    const int iend = sl < 63 ? sl : 63;
    if (ln <= iend - istart) {
      const int ig = i0 + istart + ln;
      const float Dp = Ds[istart + ln][sl - istart - ln];
      const float ef = floorf(Dp);
      const float mt = __builtin_amdgcn_exp2f(ef - Dp);  // (0.5, 1]
      const unsigned short mh =
          __builtin_bit_cast(unsigned short, (_Float16)mt);
      Db[Bclosed(i0 + j0 + sl) + ig] = ((unsigned)(int)ef << 16) | mh;
    }
  }
}

// DPP helpers. 0x138 = WAVE_SHR1: result[l] = src[l-1], result[0] = old[0].
// 0x130 = WAVE_SHL1: result[l] = src[l+1] ... (advance stream toward lane 0).
__device__ __forceinline__ int dpp_shr1_old_i(int oldv, int v) {
  return __builtin_amdgcn_update_dpp(oldv, v, 0x138, 0xf, 0xf, false);
}
__device__ __forceinline__ int dpp_shl1_i(int v) {
  return __builtin_amdgcn_update_dpp(v, v, 0x130, 0xf, 0xf, false);
}

// ---------------- Kernel 2: soft-DTW wavefront DP, exponential domain ------
// u(i,j) = 2^(-R'(i,j)) carried as (f32 mantissa ma, i32 exponent ea).
// Recurrence: u_new = t * (u_up1 + u_up2 + u_own) — pure full-rate VALU:
// max3_i32 exponent align + 3x ldexp + 2 add + mul; frexp renorm every 4th
// step. No transcendentals anywhere in the chain.
__global__ __launch_bounds__(512) void softdtw_kernel(
    const unsigned* __restrict__ Dsk, float* __restrict__ out) {
  const int b = blockIdx.x;
  const int t = threadIdx.x;
  const int wu = __builtin_amdgcn_readfirstlane(t >> 6);
  const int lane = t & 63;
  const int blk = ((wu & 3) << 1) | (wu >> 2);  // row-block 0..7

  __shared__ float2 bbuf[WAVES][BBSTRIDE];  // boundary rows as (m, e) pairs

  for (int k = t; k < WAVES * BBSTRIDE; k += 512)
    (&bbuf[0][0])[k] = make_float2(0.0f, __int_as_float(EMIN));
  __syncthreads();

  const unsigned* __restrict__ Du = Dsk + (size_t)b * DIAGELEMS;
  const int r = 64 * blk + lane;  // 0-based row; cell row i = r+1

  float ma = 0.0f;  int ea = EMIN;   // own u = R'[i][j-1]  (init: inf)
  float u2m; int u2e;                // up2 pair (prev step's up1)
  if (blk == 0 && lane == 0) { u2m = 1.0f; u2e = 0; }  // R'[0][0] = 0
  else { u2m = 0.0f; u2e = EMIN; }

  unsigned dvA[CSPAN], dvB[CSPAN];

#define FILL(ARR, Q)                                           \
  do {                                                         \
    const int q_ = (Q);                                        \
    _Pragma("unroll") for (int k_ = 0; k_ < CSPAN; ++k_) {     \
      int s_ = 32 * q_ + k_;                                   \
      s_ = s_ > 1022 ? 1022 : s_;                              \
      int e_ = Bclosed(s_) + r;                                \
      e_ = e_ > DIAGELEMS - 1 ? DIAGELEMS - 1 : e_;            \
      ARR[k_] = Du[e_];                                        \
    }                                                          \
  } while (0)

#define STEP_CORE(PK)                                                   \
  int u1m_i = dpp_shr1_old_i(__float_as_int(Bm), __float_as_int(ma));   \
  int u1e = dpp_shr1_old_i(Be, ea);                                     \
  Bm = __int_as_float(dpp_shl1_i(__float_as_int(Bm)));                  \
  Be = dpp_shl1_i(Be);                                                  \
  const float u1m = __int_as_float(u1m_i);                              \
  const float mt =                                                      \
      (float)__builtin_bit_cast(_Float16, (unsigned short)((PK)&0xffffu)); \
  const int et = (int)((PK) >> 16);                                     \
  int emax = max(max(u1e, u2e), ea);                                    \
  float ssum = ldexpf(u1m, u1e - emax) + ldexpf(u2m, u2e - emax) +      \
               ldexpf(ma, ea - emax);                                   \
  float mraw = ssum * mt;                                               \
  int eraw = emax - et;                                                 \
  u2m = u1m;                                                            \
  u2e = u1e;

#define PHASE(DVC, DVN)                                                 \
  do {                                                                  \
    if (cc + 1 < SPW) FILL(DVN, c + 1);                                 \
    __builtin_amdgcn_sched_barrier(0);                                  \
    float Bm; int Be;                                                   \
    if (blk) {                                                          \
      int bi = BBPAD + 32 * cc + 1 + lane;                              \
      bi = bi > BBSTRIDE - 1 ? BBSTRIDE - 1 : bi;                       \
      const float2 Bv = bbuf[blk][bi];                                  \
      Bm = Bv.x; Be = __float_as_int(Bv.y);                             \
    } else {                                                            \
      Bm = 0.0f; Be = EMIN;                                             \
    }                                                                   \
    float2* pubp = &bbuf[(blk + 1) & 7][BBPAD + 32 * c - r + 1];        \
    if (cc >= 2 && cc <= 15) { /* all lanes active at all steps */      \
      _Pragma("unroll") for (int k = 0; k < CSPAN; ++k) {               \
        STEP_CORE(DVC[k]);                                              \
        if ((k & 3) == 3) { int ex_; mraw = frexpf(mraw, &ex_); eraw += ex_; } \
        ma = mraw; ea = eraw;                                           \
        pubp[k] = make_float2(ma, __int_as_float(ea));                  \
      }                                                                 \
    } else { /* edge phases: mask inactive columns */                   \
      const int jv0 = 32 * c - r + 1;                                   \
      _Pragma("unroll") for (int k = 0; k < CSPAN; ++k) {               \
        STEP_CORE(DVC[k]);                                              \
        if ((k & 3) == 3) { int ex_; mraw = frexpf(mraw, &ex_); eraw += ex_; } \
        const bool a0 = (unsigned)(jv0 + k - 1) < (unsigned)MM;         \
        ma = a0 ? mraw : ma;                                            \
        ea = a0 ? eraw : ea;                                            \
        pubp[k] = make_float2(ma, __int_as_float(ea));                  \
      }                                                                 \
    }                                                                   \
  } while (0)

  // prefill current buffer with this block's first span (2*blk)
  FILL(dvA, 2 * blk);
  __builtin_amdgcn_sched_barrier(0);

  for (int S = 0; S < TPH; ++S) {
    const int cc = S - 3 * blk;  // phase-local span index
    if (cc >= 0 && cc < SPW) {
      const int c = cc + 2 * blk;  // global span (<= 31)
      if (cc & 1) {
        PHASE(dvB, dvA);
      } else {
        PHASE(dvA, dvB);
      }
    }
    __syncthreads();
  }

  // u = ma * 2^ea = 2^(-R');  out = R' * ln2
  if (blk == WAVES - 1 && lane == 63)
    out[b] = -(__builtin_amdgcn_logf(ma) + (float)ea) * LN2F;
}

extern "C" void kernel_launch(void* const* d_in, const int* in_sizes, int n_in,
                              void* d_out, int out_size, void* d_ws,
                              size_t ws_size, hipStream_t stream) {
  const float* X = (const float*)d_in[0];
  const float* Y = (const float*)d_in[1];
  float* out = (float*)d_out;
  unsigned* Dsk = (unsigned*)d_ws;

  const size_t needed = (size_t)NB * DIAGELEMS * sizeof(unsigned);
  if (ws_size < needed) return;

  pairdist_kernel<<<dim3(MM / 64, NN / 64, NB), 256, 0, stream>>>(X, Y, Dsk);
  softdtw_kernel<<<NB, 512, 0, stream>>>(Dsk, out);
}

// Round 9
// 165.675 us; speedup vs baseline: 1.1026x; 1.1026x over previous
//
#include <hip/hip_runtime.h>

#define LOG2E 1.4426950408889634f
#define LN2F 0.6931471805599453f

constexpr int NB = 16;    // batches
constexpr int NN = 512;   // N rows
constexpr int MM = 512;   // M cols
constexpr int KD = 64;    // feature dim
constexpr int WAVES = 8;                     // 512 threads, 1 row/lane
constexpr int CSPAN = 32;                    // diagonals per barrier phase
constexpr int NSPANS = 32;
constexpr int SPW = 18;                      // spans per 64-row block
constexpr int TPH = 3 * (WAVES - 1) + SPW;   // 39 barrier phases
constexpr int DIAGELEMS = NN * MM;
constexpr int EMIN = -(1 << 18);             // exponent of u==0 ("R'=inf")
#define PINF ((int)((unsigned)EMIN << 12))   // packed zero/inf

constexpr int BBSTRIDE = 672;  // bbuf row: columns [-62, 609] at idx 62+j
constexpr int BUFD_U32 = WAVES * 2 * CSPAN * 64;   // 32768 (128 KiB)
constexpr int BBUF_U32 = WAVES * BBSTRIDE;         // 5376  (21 KiB)
constexpr int SMEM_BYTES = (BUFD_U32 + BBUF_U32) * 4;  // 152576

// Packed anti-diagonal layout: element (i,j) [0-based] lives at
// Dsk[b*DIAGELEMS + B(s) + i],  s = i+j.
__device__ __forceinline__ int Bclosed(int s) {
  return (s <= 511) ? (s * (s + 1)) / 2
                    : DIAGELEMS - ((1023 - s) * (1024 - s)) / 2 - (s - 511);
}

// ---------------- Kernel 1: pairwise distances -> packed t = 2^(-D') -------
// D' = min(dist^2,1e4)*log2e.  t packed as Pt = (et<<12)|mut, value
// mut*2^(et-12), mut in (2048,4095], et = -floor(D').
__global__ __launch_bounds__(256) void pairdist_kernel(
    const float* __restrict__ X, const float* __restrict__ Y,
    unsigned* __restrict__ Dsk) {
  const int b = blockIdx.z;
  const int i0 = blockIdx.y * 64;
  const int j0 = blockIdx.x * 64;

  __shared__ float Xs[64][65];
  __shared__ float Ys[64][65];
  __shared__ unsigned Ds[64][66];  // packed; stride 66: diag reads conflict-free

  const float* Xb = X + ((size_t)b * NN + i0) * KD;
  const float* Yb = Y + ((size_t)b * MM + j0) * KD;
  for (int k = threadIdx.x; k < 64 * KD; k += 256) {
    Xs[k >> 6][k & 63] = Xb[k];
    Ys[k >> 6][k & 63] = Yb[k];
  }
  __syncthreads();

  const int tx = threadIdx.x & 15;
  const int ty = threadIdx.x >> 4;
  const int r0 = ty * 4, c0 = tx * 4;

  float acc[4][4];
#pragma unroll
  for (int a = 0; a < 4; ++a)
#pragma unroll
    for (int e = 0; e < 4; ++e) acc[a][e] = 0.0f;

  for (int d = 0; d < KD; ++d) {
    float xv[4], yv[4];
#pragma unroll
    for (int q = 0; q < 4; ++q) xv[q] = Xs[r0 + q][d];
#pragma unroll
    for (int q = 0; q < 4; ++q) yv[q] = Ys[c0 + q][d];
#pragma unroll
    for (int a = 0; a < 4; ++a)
#pragma unroll
      for (int e = 0; e < 4; ++e) {
        float df = xv[a] - yv[e];
        acc[a][e] = fmaf(df, df, acc[a][e]);
      }
  }

#pragma unroll
  for (int a = 0; a < 4; ++a)
#pragma unroll
    for (int e = 0; e < 4; ++e) {
      const float Dp = fminf(acc[a][e], 10000.0f) * LOG2E;
      const float ef = floorf(Dp);
      const float mt = __builtin_amdgcn_exp2f(ef - Dp);  // (0.5, 1]
      const unsigned mut = min(4095u, (unsigned)(mt * 4096.0f));
      const int et = -(int)ef;
      Ds[r0 + a][c0 + e] = ((unsigned)et << 12) | mut;
    }
  __syncthreads();

  // diag-major coalesced stores: wave handles diag sl, 64 lanes = 1 segment
  const int wv = threadIdx.x >> 6;
  const int ln = threadIdx.x & 63;
  unsigned* Db = Dsk + (size_t)b * DIAGELEMS;
  for (int sl = wv; sl < 127; sl += 4) {
    const int istart = sl > 63 ? sl - 63 : 0;
    const int iend = sl < 63 ? sl : 63;
    if (ln <= iend - istart) {
      const int ig = i0 + istart + ln;  // global row
      Db[Bclosed(i0 + j0 + sl) + ig] = Ds[istart + ln][sl - istart - ln];
    }
  }
}

// DPP helpers. 0x138 = WAVE_SHR1: res[l] = src[l-1], res[0] = old[0].
// 0x130 = WAVE_SHL1: res[l] = src[l+1] (advance stream toward lane 0).
__device__ __forceinline__ int dpp_shr1_old_i(int oldv, int v) {
  return __builtin_amdgcn_update_dpp(oldv, v, 0x138, 0xf, 0xf, false);
}
__device__ __forceinline__ int dpp_shl1_i(int v) {
  return __builtin_amdgcn_update_dpp(v, v, 0x130, 0xf, 0xf, false);
}

// DMA one span's D-block (32 steps x 64 rows) for row-block blk into LDS.
__device__ __forceinline__ void dma_span(const unsigned* __restrict__ Dskb,
                                         unsigned* bufD, int blk, int q,
                                         int lane) {
  unsigned* dst0 = bufD + (blk * 2 + (q & 1)) * (CSPAN * 64);
  const int rbase = 64 * blk + (lane & 15) * 4;
  const int sub = lane >> 4;
#pragma unroll
  for (int u = 0; u < 8; ++u) {
    int s = 32 * q + 4 * u + sub;
    s = s > 1022 ? 1022 : s;
    int e = Bclosed(s) + rbase;
    e = e > DIAGELEMS - 4 ? DIAGELEMS - 4 : e;  // junk rows masked later
    __builtin_amdgcn_global_load_lds(
        (const __attribute__((address_space(1))) void*)(Dskb + e),
        (__attribute__((address_space(3))) void*)(dst0 + u * 256), 16, 0, 0);
  }
}

// Packed exp-domain softmin step: u_new = t*(u1+u2+u0), all integer ALU.
// P=(e<<12)|mu, value mu*2^(e-12), mu in [2048,4095] or 0 (with e=EMIN).
#define SOFTMIN_STEP(PK)                                                    \
  {                                                                         \
    const int up1P = dpp_shr1_old_i(B, P); /* R'[i-1][j] packed */          \
    B = dpp_shl1_i(B);                                                      \
    const int e1 = up1P >> 12;                                              \
    const unsigned mu1 = (unsigned)up1P & 4095u;                            \
    const int emax = max(max(e1, e2), e0);                                  \
    const unsigned sh1 = min((unsigned)(emax - e1), 31u);                   \
    const unsigned sh2 = min((unsigned)(emax - e2), 31u);                   \
    const unsigned sh0 = min((unsigned)(emax - e0), 31u);                   \
    const unsigned ssum = (mu1 >> sh1) + (mu2 >> sh2) + (mu0 >> sh0);       \
    const int et = ((int)(PK)) >> 12;                                       \
    const unsigned mut = (PK)&4095u;                                        \
    const unsigned prod = __umul24(ssum, mut); /* [2^22, 2^25.6] or 0 */    \
    const int lz = __builtin_clz(prod | 1u);                                \
    nmu = prod >> (unsigned)(20 - lz); /* normalize to [2048,4095] */       \
    ne = emax + et + (8 - lz);                                              \
    nP = (int)(((unsigned)ne << 12) + nmu);                                 \
    e2 = e1;                                                                \
    mu2 = mu1;                                                              \
  }

// ---------------- Kernel 2: soft-DTW wavefront DP, packed exp domain -------
// One block per batch, 8 waves x 64 lanes, 1 row per lane (2 waves/SIMD).
// Step loop: 2 DPP + ~22 full-rate int ALU + 1 ds_write. No transcendentals.
extern __shared__ unsigned usmem[];
__global__ __launch_bounds__(512) void softdtw_kernel(
    const unsigned* __restrict__ Dsk, float* __restrict__ out) {
  const int b = blockIdx.x;
  const int t = threadIdx.x;
  const int wu = __builtin_amdgcn_readfirstlane(t >> 6);
  const int lane = t & 63;
  const int blk = ((wu & 3) << 1) | (wu >> 2);  // row-block 0..7

  unsigned* bufD = usmem;               // [8][2][32][64]
  unsigned* bbuf = usmem + BUFD_U32;    // [8][672]: row w col j at [w][62+j]

  for (int k = t; k < BBUF_U32; k += 512) bbuf[k] = (unsigned)PINF;
  __syncthreads();

  const unsigned* __restrict__ Dskb = Dsk + (size_t)b * DIAGELEMS;

  // pre-issue DMA for this block's first span (parity (2*blk)&1 == 0)
  dma_span(Dskb, bufD, blk, 2 * blk, lane);

  const int r = 64 * blk + lane;  // 0-based row; cell row i = r+1
  int P = PINF;                   // own u = 2^(-R'[i][j-1]) packed (init 0)
  int e0 = EMIN;
  unsigned mu0 = 0;
  // u2 = R'[i-1][j-1] = previous step's up1; seed origin R'[0][0]=0 (u=1).
  int e2;
  unsigned mu2;
  if (blk == 0 && lane == 0) { e2 = 1; mu2 = 2048; }  // 2048*2^(1-12) = 1.0
  else { e2 = EMIN; mu2 = 0; }

  for (int S = 0; S < TPH; ++S) {
    const int cc = S - 3 * blk;  // phase-local span index
    if (cc >= 0 && cc < SPW) {
      const int c = cc + 2 * blk;  // global span (<= 31)
      if (cc + 1 < SPW) {
        dma_span(Dskb, bufD, blk, c + 1, lane);
        asm volatile("s_waitcnt vmcnt(8)" ::: "memory");  // span-c DMA done
      } else {
        asm volatile("s_waitcnt vmcnt(0)" ::: "memory");
      }

      // boundary stream: B[lane] = packed R'[64blk][32cc+1+lane]; step k
      // consumes B-orig[k] (k<=31) via lane0 of the dpp old-operand.
      int B = PINF;
      if (blk) {
        int bi = 62 + 32 * cc + 1 + lane;
        bi = bi > BBSTRIDE - 1 ? BBSTRIDE - 1 : bi;
        B = (int)bbuf[blk * BBSTRIDE + bi];
      }

      const unsigned* myD = bufD + (blk * 2 + (c & 1)) * (CSPAN * 64);
      const __attribute__((address_space(3))) unsigned* mp =
          (const __attribute__((address_space(3))) unsigned*)(myD + lane);
      unsigned maddr = (unsigned)(size_t)mp;

      unsigned dv[CSPAN];
      asm volatile(
          "ds_read_b32 %0, %32 offset:0\n\t"
          "ds_read_b32 %1, %32 offset:256\n\t"
          "ds_read_b32 %2, %32 offset:512\n\t"
          "ds_read_b32 %3, %32 offset:768\n\t"
          "ds_read_b32 %4, %32 offset:1024\n\t"
          "ds_read_b32 %5, %32 offset:1280\n\t"
          "ds_read_b32 %6, %32 offset:1536\n\t"
          "ds_read_b32 %7, %32 offset:1792\n\t"
          "ds_read_b32 %8, %32 offset:2048\n\t"
          "ds_read_b32 %9, %32 offset:2304\n\t"
          "ds_read_b32 %10, %32 offset:2560\n\t"
          "ds_read_b32 %11, %32 offset:2816\n\t"
          "ds_read_b32 %12, %32 offset:3072\n\t"
          "ds_read_b32 %13, %32 offset:3328\n\t"
          "ds_read_b32 %14, %32 offset:3584\n\t"
          "ds_read_b32 %15, %32 offset:3840\n\t"
          "ds_read_b32 %16, %32 offset:4096\n\t"
          "ds_read_b32 %17, %32 offset:4352\n\t"
          "ds_read_b32 %18, %32 offset:4608\n\t"
          "ds_read_b32 %19, %32 offset:4864\n\t"
          "ds_read_b32 %20, %32 offset:5120\n\t"
          "ds_read_b32 %21, %32 offset:5376\n\t"
          "ds_read_b32 %22, %32 offset:5632\n\t"
          "ds_read_b32 %23, %32 offset:5888\n\t"
          "ds_read_b32 %24, %32 offset:6144\n\t"
          "ds_read_b32 %25, %32 offset:6400\n\t"
          "ds_read_b32 %26, %32 offset:6656\n\t"
          "ds_read_b32 %27, %32 offset:6912\n\t"
          "ds_read_b32 %28, %32 offset:7168\n\t"
          "ds_read_b32 %29, %32 offset:7424\n\t"
          "ds_read_b32 %30, %32 offset:7680\n\t"
          "ds_read_b32 %31, %32 offset:7936\n\t"
          "s_waitcnt lgkmcnt(0)"
          : "=&v"(dv[0]), "=&v"(dv[1]), "=&v"(dv[2]), "=&v"(dv[3]),
            "=&v"(dv[4]), "=&v"(dv[5]), "=&v"(dv[6]), "=&v"(dv[7]),
            "=&v"(dv[8]), "=&v"(dv[9]), "=&v"(dv[10]), "=&v"(dv[11]),
            "=&v"(dv[12]), "=&v"(dv[13]), "=&v"(dv[14]), "=&v"(dv[15]),
            "=&v"(dv[16]), "=&v"(dv[17]), "=&v"(dv[18]), "=&v"(dv[19]),
            "=&v"(dv[20]), "=&v"(dv[21]), "=&v"(dv[22]), "=&v"(dv[23]),
            "=&v"(dv[24]), "=&v"(dv[25]), "=&v"(dv[26]), "=&v"(dv[27]),
            "=&v"(dv[28]), "=&v"(dv[29]), "=&v"(dv[30]), "=&v"(dv[31])
          : "v"(maddr)
          : "memory");

      // unmasked publish: lane 63 (true boundary row 64(blk+1)) is provably
      // the LAST writer of every column the next block consumes; blk 7
      // dumps to row 0 (never read).
      unsigned* pubp =
          bbuf + ((blk + 1) & 7) * BBSTRIDE + (62 + 32 * c - r + 1);

      int nP, ne;
      unsigned nmu;
      if (cc >= 2 && cc <= 15) {  // all 64 lanes active at all 32 steps
#pragma unroll
        for (int k = 0; k < CSPAN; ++k) {
          SOFTMIN_STEP(dv[k]);
          P = nP;
          e0 = ne;
          mu0 = nmu;
          pubp[k] = (unsigned)P;
        }
      } else {  // edge phases: keep activity mask
        const int jv0 = 32 * c - r + 1;
#pragma unroll
        for (int k = 0; k < CSPAN; ++k) {
          SOFTMIN_STEP(dv[k]);
          const bool a0 = (unsigned)(jv0 + k - 1) < (unsigned)MM;
          P = a0 ? nP : P;
          e0 = a0 ? ne : e0;
          mu0 = a0 ? nmu : mu0;
          pubp[k] = (unsigned)P;
        }
      }
    }
    __syncthreads();
  }

  // u = mu0 * 2^(e0-12);  R' = -(log2(mu0) + e0 - 12);  out = R' * ln2
  if (blk == WAVES - 1 && lane == 63)
    out[b] = ((float)(12 - e0) - __builtin_amdgcn_logf((float)mu0)) * LN2F;
}

extern "C" void kernel_launch(void* const* d_in, const int* in_sizes, int n_in,
                              void* d_out, int out_size, void* d_ws,
                              size_t ws_size, hipStream_t stream) {
  const float* X = (const float*)d_in[0];
  const float* Y = (const float*)d_in[1];
  float* out = (float*)d_out;
  unsigned* Dsk = (unsigned*)d_ws;

  const size_t needed = (size_t)NB * DIAGELEMS * sizeof(unsigned);
  if (ws_size < needed) return;

  hipFuncSetAttribute((const void*)softdtw_kernel,
                      hipFuncAttributeMaxDynamicSharedMemorySize, SMEM_BYTES);

  pairdist_kernel<<<dim3(MM / 64, NN / 64, NB), 256, 0, stream>>>(X, Y, Dsk);
  softdtw_kernel<<<NB, 512, SMEM_BYTES, stream>>>(Dsk, out);
}

// Round 10
// 135.242 us; speedup vs baseline: 1.3507x; 1.2250x over previous
//
#include <hip/hip_runtime.h>

#define BIGF 1e30f
#define LOG2E 1.4426950408889634f
#define LN2F 0.6931471805599453f

constexpr int NB = 16;    // batches
constexpr int NN = 512;   // N rows
constexpr int MM = 512;   // M cols
constexpr int KD = 64;    // feature dim
constexpr int WAVES = 8;                     // 512 threads, 1 row/lane
constexpr int CSPAN = 32;                    // diagonals per barrier phase
constexpr int NSPANS = 32;                   // 1023 diagonals / 32
constexpr int SPW = 18;                      // spans per 64-row block
constexpr int TPH = 3 * (WAVES - 1) + SPW;   // 39 barrier phases
constexpr int DIAGELEMS = NN * MM;

// bbuf row covers columns [-62, 609] -> index = 62 + j, stride 672.
constexpr int BBSTRIDE = 672;
constexpr int BUFD_FLOATS = WAVES * 2 * CSPAN * 64;   // 32768 (128 KiB)
constexpr int BBUF_FLOATS = WAVES * BBSTRIDE;         // 5376  (21 KiB)
constexpr int SMEM_BYTES = (BUFD_FLOATS + BBUF_FLOATS) * 4;  // 152576

// Packed anti-diagonal layout: element (i,j) [0-based] lives at
// Dsk[b*DIAGELEMS + B(s) + i],  s = i+j.
__device__ __forceinline__ int Bclosed(int s) {
  return (s <= 511) ? (s * (s + 1)) / 2
                    : DIAGELEMS - ((1023 - s) * (1024 - s)) / 2 - (s - 511);
}

// ---------------- Kernel 1: pairwise squared distances (exp2-domain) -------
__global__ __launch_bounds__(256) void pairdist_kernel(
    const float* __restrict__ X, const float* __restrict__ Y,
    float* __restrict__ Dsk) {
  const int b = blockIdx.z;
  const int i0 = blockIdx.y * 64;
  const int j0 = blockIdx.x * 64;

  __shared__ float Xs[64][65];
  __shared__ float Ys[64][65];
  __shared__ float Ds[64][66];  // stride 66: diag reads (stride 65) conflict-free

  const float* Xb = X + ((size_t)b * NN + i0) * KD;
  const float* Yb = Y + ((size_t)b * MM + j0) * KD;
  for (int k = threadIdx.x; k < 64 * KD; k += 256) {
    Xs[k >> 6][k & 63] = Xb[k];
    Ys[k >> 6][k & 63] = Yb[k];
  }
  __syncthreads();

  const int tx = threadIdx.x & 15;
  const int ty = threadIdx.x >> 4;
  const int r0 = ty * 4, c0 = tx * 4;

  float acc[4][4];
#pragma unroll
  for (int a = 0; a < 4; ++a)
#pragma unroll
    for (int e = 0; e < 4; ++e) acc[a][e] = 0.0f;

  for (int d = 0; d < KD; ++d) {
    float xv[4], yv[4];
#pragma unroll
    for (int q = 0; q < 4; ++q) xv[q] = Xs[r0 + q][d];
#pragma unroll
    for (int q = 0; q < 4; ++q) yv[q] = Ys[c0 + q][d];
#pragma unroll
    for (int a = 0; a < 4; ++a)
#pragma unroll
      for (int e = 0; e < 4; ++e) {
        float df = xv[a] - yv[e];
        acc[a][e] = fmaf(df, df, acc[a][e]);
      }
  }

#pragma unroll
  for (int a = 0; a < 4; ++a)
#pragma unroll
    for (int e = 0; e < 4; ++e)
      Ds[r0 + a][c0 + e] = fminf(acc[a][e], 10000.0f) * LOG2E;
  __syncthreads();

  // diag-major coalesced stores: wave handles diag sl, 64 lanes = 1 segment
  const int wv = threadIdx.x >> 6;
  const int ln = threadIdx.x & 63;
  float* Db = Dsk + (size_t)b * DIAGELEMS;
  for (int sl = wv; sl < 127; sl += 4) {
    const int istart = sl > 63 ? sl - 63 : 0;
    const int iend = sl < 63 ? sl : 63;
    if (ln <= iend - istart) {
      const int ig = i0 + istart + ln;  // global row
      Db[Bclosed(i0 + j0 + sl) + ig] = Ds[istart + ln][sl - istart - ln];
    }
  }
}

// up1 = lane i-1's ra; lane 0 takes old[lane0] = B[lane0] (boundary inject).
__device__ __forceinline__ float dpp_shr1_old(float oldv, float v) {
  return __int_as_float(__builtin_amdgcn_update_dpp(
      __float_as_int(oldv), __float_as_int(v), 0x138 /*WAVE_SHR1*/, 0xf, 0xf,
      false));
}
// B[l] <- B[l+1] (advance boundary stream; high lanes keep junk).
__device__ __forceinline__ float dpp_shl1(float v) {
  return __int_as_float(__builtin_amdgcn_update_dpp(
      __float_as_int(v), __float_as_int(v), 0x130 /*WAVE_SHL1*/, 0xf, 0xf,
      false));
}

// Full-rate bit-hack exp2/log2 (Schraudolph, balanced bias 0.0450466).
// fexp2: max + fma + cvt_i32 (trunc) — all full-rate VALU, ~18 cy latency.
// Valid for x <= 0; clamp at -126 keeps the int positive (result ~0).
__device__ __forceinline__ float fexp2(float x) {
  x = fmaxf(x, -126.0f);
  return __int_as_float((int)fmaf(x, 8388608.0f, 1.064975338e9f));
}
// flog2: cvt_f32 + fma. Input y in [1, 4): error within +-0.043.
__device__ __forceinline__ float flog2(float y) {
  return fmaf((float)__float_as_int(y), 1.1920929e-7f, -126.9549534f);
}

// DMA one span's D-block (32 steps x 64 rows) for row-block blk into LDS.
__device__ __forceinline__ void dma_span(const float* __restrict__ Dskb,
                                         float* bufD, int blk, int q,
                                         int lane) {
  float* dst0 = bufD + (blk * 2 + (q & 1)) * (CSPAN * 64);
  const int rbase = 64 * blk + (lane & 15) * 4;
  const int sub = lane >> 4;
#pragma unroll
  for (int u = 0; u < 8; ++u) {
    int s = 32 * q + 4 * u + sub;
    s = s > 1022 ? 1022 : s;
    int e = Bclosed(s) + rbase;
    e = e > DIAGELEMS - 4 ? DIAGELEMS - 4 : e;  // junk rows masked later
    __builtin_amdgcn_global_load_lds(
        (const __attribute__((address_space(1))) void*)(Dskb + e),
        (__attribute__((address_space(3))) void*)(dst0 + u * 256), 16, 0, 0);
  }
}

#define SOFTMIN_STEP(K)                                                     \
  {                                                                         \
    const float up1 = dpp_shr1_old(B, ra);                                  \
    B = dpp_shl1(B);                                                        \
    const float m = fminf(fminf(up1, up2), ra);                             \
    const float md = __builtin_amdgcn_fmed3f(up1, up2, ra);                 \
    const float mx = fmaxf(fmaxf(up1, up2), ra);                            \
    const float ssum = (fexp2(m - md) + fexp2(m - mx)) + 1.0f;              \
    n = (dv[K] + m) - flog2(ssum);                                          \
    up2 = up1;                                                              \
  }

// ---------------- Kernel 2: soft-DTW wavefront DP (base-2 domain) ----------
// One block per batch, 8 waves x 64 lanes, 1 row per lane (2 waves/SIMD).
// Step loop: dpp, min3/med3/max3, bit-hack exp2 x2 / log2 (full-rate VALU,
// no transcendentals), unmasked ds_write publish. Boundary values stream
// through a DPP-shifting register; no readlane, no exec masking.
extern __shared__ float smem[];
__global__ __launch_bounds__(512) void softdtw_kernel(
    const float* __restrict__ Dsk, float* __restrict__ out) {
  const int b = blockIdx.x;
  const int t = threadIdx.x;
  const int wu = __builtin_amdgcn_readfirstlane(t >> 6);
  const int lane = t & 63;
  const int blk = ((wu & 3) << 1) | (wu >> 2);  // row-block 0..7

  float* bufD = smem;                // [8][2][32][64]
  float* bbuf = smem + BUFD_FLOATS;  // [8][672]: row w col j at [w][62+j]

  for (int k = t; k < BBUF_FLOATS; k += 512) bbuf[k] = BIGF;
  __syncthreads();

  const float* __restrict__ Dskb = Dsk + (size_t)b * DIAGELEMS;

  // pre-issue DMA for this block's first span (parity (2*blk)&1 == 0)
  dma_span(Dskb, bufD, blk, 2 * blk, lane);

  const int r = 64 * blk + lane;  // 0-based row; cell row i = r+1
  float ra = BIGF;                // R'[i][j-1]
  // up2 = R'[i-1][j-1] = previous step's up1; seed R'[0][0]=0 for the origin.
  float up2 = (blk == 0 && lane == 0) ? 0.0f : BIGF;

  for (int S = 0; S < TPH; ++S) {
    const int cc = S - 3 * blk;  // phase-local span index
    if (cc >= 0 && cc < SPW) {
      const int c = cc + 2 * blk;  // global span (<= 31)
      if (cc + 1 < SPW) {
        dma_span(Dskb, bufD, blk, c + 1, lane);
        asm volatile("s_waitcnt vmcnt(8)" ::: "memory");  // span-c DMA done
      } else {
        asm volatile("s_waitcnt vmcnt(0)" ::: "memory");
      }

      // boundary stream: B[lane] = R'[64blk][32cc+1+lane]; step k consumes
      // B-orig[k] (k<=31) via lane0 of the dpp old-operand.
      float B = BIGF;
      if (blk) B = bbuf[blk * BBSTRIDE + 62 + 32 * cc + 1 + lane];

      const float* myD = bufD + (blk * 2 + (c & 1)) * (CSPAN * 64);
      const __attribute__((address_space(3))) float* mp =
          (const __attribute__((address_space(3))) float*)(myD + lane);
      unsigned maddr = (unsigned)(size_t)mp;

      float dv[CSPAN];
      asm volatile(
          "ds_read_b32 %0, %32 offset:0\n\t"
          "ds_read_b32 %1, %32 offset:256\n\t"
          "ds_read_b32 %2, %32 offset:512\n\t"
          "ds_read_b32 %3, %32 offset:768\n\t"
          "ds_read_b32 %4, %32 offset:1024\n\t"
          "ds_read_b32 %5, %32 offset:1280\n\t"
          "ds_read_b32 %6, %32 offset:1536\n\t"
          "ds_read_b32 %7, %32 offset:1792\n\t"
          "ds_read_b32 %8, %32 offset:2048\n\t"
          "ds_read_b32 %9, %32 offset:2304\n\t"
          "ds_read_b32 %10, %32 offset:2560\n\t"
          "ds_read_b32 %11, %32 offset:2816\n\t"
          "ds_read_b32 %12, %32 offset:3072\n\t"
          "ds_read_b32 %13, %32 offset:3328\n\t"
          "ds_read_b32 %14, %32 offset:3584\n\t"
          "ds_read_b32 %15, %32 offset:3840\n\t"
          "ds_read_b32 %16, %32 offset:4096\n\t"
          "ds_read_b32 %17, %32 offset:4352\n\t"
          "ds_read_b32 %18, %32 offset:4608\n\t"
          "ds_read_b32 %19, %32 offset:4864\n\t"
          "ds_read_b32 %20, %32 offset:5120\n\t"
          "ds_read_b32 %21, %32 offset:5376\n\t"
          "ds_read_b32 %22, %32 offset:5632\n\t"
          "ds_read_b32 %23, %32 offset:5888\n\t"
          "ds_read_b32 %24, %32 offset:6144\n\t"
          "ds_read_b32 %25, %32 offset:6400\n\t"
          "ds_read_b32 %26, %32 offset:6656\n\t"
          "ds_read_b32 %27, %32 offset:6912\n\t"
          "ds_read_b32 %28, %32 offset:7168\n\t"
          "ds_read_b32 %29, %32 offset:7424\n\t"
          "ds_read_b32 %30, %32 offset:7680\n\t"
          "ds_read_b32 %31, %32 offset:7936\n\t"
          "s_waitcnt lgkmcnt(0)"
          : "=&v"(dv[0]), "=&v"(dv[1]), "=&v"(dv[2]), "=&v"(dv[3]),
            "=&v"(dv[4]), "=&v"(dv[5]), "=&v"(dv[6]), "=&v"(dv[7]),
            "=&v"(dv[8]), "=&v"(dv[9]), "=&v"(dv[10]), "=&v"(dv[11]),
            "=&v"(dv[12]), "=&v"(dv[13]), "=&v"(dv[14]), "=&v"(dv[15]),
            "=&v"(dv[16]), "=&v"(dv[17]), "=&v"(dv[18]), "=&v"(dv[19]),
            "=&v"(dv[20]), "=&v"(dv[21]), "=&v"(dv[22]), "=&v"(dv[23]),
            "=&v"(dv[24]), "=&v"(dv[25]), "=&v"(dv[26]), "=&v"(dv[27]),
            "=&v"(dv[28]), "=&v"(dv[29]), "=&v"(dv[30]), "=&v"(dv[31])
          : "v"(maddr)
          : "memory");

      // unmasked publish target: column jv(k) = 32c - r + 1 + k.
      // Lane 63 (the true boundary row 64(blk+1)) is provably the LAST
      // writer of every column the next block consumes; blk 7 dumps to
      // row 0 (never read).
      float* pubp =
          bbuf + ((blk + 1) & 7) * BBSTRIDE + (62 + 32 * c - r + 1);

      float n;
      if (cc >= 2 && cc <= 15) {  // all 64 lanes active at all 32 steps
#pragma unroll
        for (int k = 0; k < CSPAN; ++k) {
          SOFTMIN_STEP(k);
          ra = n;
          pubp[k] = ra;
        }
      } else {  // edge phases: keep activity mask
        const int jv0 = 32 * c - r + 1;
#pragma unroll
        for (int k = 0; k < CSPAN; ++k) {
          SOFTMIN_STEP(k);
          const bool a0 = (unsigned)(jv0 + k - 1) < (unsigned)MM;
          ra = a0 ? n : ra;
          pubp[k] = ra;
        }
      }
    }
    __syncthreads();
  }

  if (blk == WAVES - 1 && lane == 63) out[b] = ra * LN2F;  // R'[512][512]
}

extern "C" void kernel_launch(void* const* d_in, const int* in_sizes, int n_in,
                              void* d_out, int out_size, void* d_ws,
                              size_t ws_size, hipStream_t stream) {
  const float* X = (const float*)d_in[0];
  const float* Y = (const float*)d_in[1];
  float* out = (float*)d_out;
  float* Dsk = (float*)d_ws;

  const size_t needed = (size_t)NB * DIAGELEMS * sizeof(float);
  if (ws_size < needed) return;

  hipFuncSetAttribute((const void*)softdtw_kernel,
                      hipFuncAttributeMaxDynamicSharedMemorySize, SMEM_BYTES);

  pairdist_kernel<<<dim3(MM / 64, NN / 64, NB), 256, 0, stream>>>(X, Y, Dsk);
  softdtw_kernel<<<NB, 512, SMEM_BYTES, stream>>>(Dsk, out);
}